// Round 26
// baseline (57.209 us; speedup 1.0000x reference)
//
#include <hip/hip_runtime.h>

#define ND 1024
#define NNE (ND*ND)

typedef float f32x4 __attribute__((ext_vector_type(4)));
typedef int i32x4 __attribute__((ext_vector_type(4)));
typedef int i32x8 __attribute__((ext_vector_type(8)));

__device__ __forceinline__ void gload_lds16(const void* g, void* l) {
  __builtin_amdgcn_global_load_lds(
      (const __attribute__((address_space(1))) void*)g,
      (__attribute__((address_space(3))) void*)l, 16, 0, 0);
}

// ==== fused prep: 512 transpose blocks + 256 convert/phi0 blocks ====
// transpose grid: j = blk&7 -> psi^T[j] written from XCD j (round-robin
// dispatch), so each 1 MB psi^T[j] stays in XCD j's local L2 for the
// j-pure GEMM readers.
__global__ __launch_bounds__(256)
void prep_kernel(const float* __restrict__ psi, unsigned char* __restrict__ out8,
                 const float* __restrict__ x, const float* __restrict__ lp,
                 unsigned char* __restrict__ x8, float* __restrict__ phi) {
  __shared__ __align__(16) unsigned char T[128 * 144];
  __shared__ float ws[4];
  const int blk = blockIdx.x;
  const int tid = threadIdx.x;

  if (blk >= 512) {
    int row = blk - 512;
    if (tid >= 1 && tid < 73) phi[row * 73 + tid] = 0.f;
    float4 v = reinterpret_cast<const float4*>(x + (size_t)row * ND)[tid];
    float4 l = reinterpret_cast<const float4*>(lp)[tid];
    int pk = __builtin_amdgcn_cvt_pk_fp8_f32(v.x, v.y, 0, false);
    pk = __builtin_amdgcn_cvt_pk_fp8_f32(v.z, v.w, pk, true);
    reinterpret_cast<unsigned int*>(x8 + (size_t)row * ND)[tid] = (unsigned int)pk;
    float s = v.x * l.x + v.y * l.y + v.z * l.z + v.w * l.w;
    #pragma unroll
    for (int off = 32; off; off >>= 1) s += __shfl_xor(s, off);
    if ((tid & 63) == 0) ws[tid >> 6] = s;
    __syncthreads();
    if (tid == 0) phi[row * 73] = ws[0] + ws[1] + ws[2] + ws[3];
    return;
  }

  const int j  = blk & 7;              // XCD-pure writer for psi^T[j]
  const int t6 = blk >> 3;             // 0..63
  const int tn = t6 >> 3, tm = t6 & 7;
  const int n0 = tn * 128, m0 = tm * 128;
  const float* src = psi + ((size_t)j << 20) + (size_t)n0 * ND + m0;

  const int rgrp = tid >> 5;
  const int c4   = (tid & 31) << 2;
  #pragma unroll
  for (int it = 0; it < 16; ++it) {
    int nl = it * 8 + rgrp;
    float4 v = *reinterpret_cast<const float4*>(src + (size_t)nl * ND + c4);
    int p01 = __builtin_amdgcn_cvt_pk_fp8_f32(v.x, v.y, 0, false);
    int p23 = __builtin_amdgcn_cvt_pk_fp8_f32(v.z, v.w, 0, false);
    T[(c4 + 0) * 144 + nl] = (unsigned char)(p01 & 0xff);
    T[(c4 + 1) * 144 + nl] = (unsigned char)((p01 >> 8) & 0xff);
    T[(c4 + 2) * 144 + nl] = (unsigned char)(p23 & 0xff);
    T[(c4 + 3) * 144 + nl] = (unsigned char)((p23 >> 8) & 0xff);
  }
  __syncthreads();

  unsigned char* dst = out8 + ((size_t)j << 20) + (size_t)m0 * ND + n0;
  const int mrow = tid >> 3;
  const int ch   = (tid & 7) << 4;
  #pragma unroll
  for (int it = 0; it < 4; ++it) {
    int ml = it * 32 + mrow;
    uint4 v = *reinterpret_cast<const uint4*>(&T[ml * 144 + ch]);
    *reinterpret_cast<uint4*>(dst + (size_t)ml * ND + ch) = v;
  }
}

// one 32B fp8 fragment from swizzled LDS (two ds_read_b128, k-order preserved)
__device__ __forceinline__ i32x8 dsr_frag8(const unsigned char* base, int r, int l4) {
  int s0 = l4 * 2;
  i32x4 lo = *reinterpret_cast<const i32x4*>(base + r * 128 + ((s0 ^ (r & 7)) << 4));
  i32x4 hi = *reinterpret_cast<const i32x4*>(base + r * 128 + (((s0 + 1) ^ (r & 7)) << 4));
  return __builtin_shufflevector(lo, hi, 0, 1, 2, 3, 4, 5, 6, 7);
}

// ==== layer-1: MX-fp8, 64x128 tile, 256 blocks (full GPU), LDS dbuf ====
__device__ __forceinline__ void stage_l1(const unsigned char* __restrict__ A, int row0,
                                         const unsigned char* __restrict__ Bj, int n0,
                                         int k0, unsigned char* As, unsigned char* Bs,
                                         int tid) {
  #pragma unroll
  for (int p = 0; p < 2; ++p) {
    int c = p * 256 + tid;
    int r = c >> 3;
    int s = (c & 7) ^ (r & 7);
    gload_lds16(A + (size_t)(row0 + r) * ND + k0 + (s << 4), As + c * 16);
  }
  #pragma unroll
  for (int p = 0; p < 4; ++p) {
    int c = p * 256 + tid;
    int r = c >> 3;
    int s = (c & 7) ^ (r & 7);
    gload_lds16(Bj + (size_t)(n0 + r) * ND + k0 + (s << 4), Bs + c * 16);
  }
}

__global__ __launch_bounds__(256, 2)
void gemm8_l1(const unsigned char* __restrict__ A,
              const unsigned char* __restrict__ BT,
              const float* __restrict__ lowpass,
              unsigned char* __restrict__ Sout,
              float* __restrict__ phi) {
  __shared__ __align__(16) unsigned char As0[64 * 128];
  __shared__ __align__(16) unsigned char As1[64 * 128];
  __shared__ __align__(16) unsigned char Bs0[128 * 128];
  __shared__ __align__(16) unsigned char Bs1[128 * 128];

  const int tid  = threadIdx.x;
  const int lane = tid & 63;
  const int w    = tid >> 6;
  const int wrow = w >> 1, wcol = w & 1;
  const int l15  = lane & 15, l4 = lane >> 4;

  const int wg = blockIdx.x;
  const int j  = wg & 7;
  const int t  = wg >> 3;
  const int mtile = t & 3, ntile = t >> 2;
  const int row0 = mtile * 64, n0 = ntile * 128;
  const unsigned char* Bj = BT + (size_t)j * NNE;

  f32x4 acc[2][4] = {};

  stage_l1(A, row0, Bj, n0, 0, As0, Bs0, tid);
  __syncthreads();

  #pragma unroll 1
  for (int k0 = 0; k0 < ND; k0 += 128) {
    const int cur = (k0 >> 7) & 1;
    const unsigned char* Ac = cur ? As1 : As0;
    const unsigned char* Bc = cur ? Bs1 : Bs0;
    if (k0 + 128 < ND)
      stage_l1(A, row0, Bj, n0, k0 + 128, cur ? As0 : As1, cur ? Bs0 : Bs1, tid);
    i32x8 b[4];
    #pragma unroll
    for (int n = 0; n < 4; ++n)
      b[n] = dsr_frag8(Bc, wcol * 64 + n * 16 + l15, l4);
    #pragma unroll
    for (int m = 0; m < 2; ++m) {
      i32x8 a = dsr_frag8(Ac, wrow * 32 + m * 16 + l15, l4);
      #pragma unroll
      for (int n = 0; n < 4; ++n)
        acc[m][n] = __builtin_amdgcn_mfma_scale_f32_16x16x128_f8f6f4(
            a, b[n], acc[m][n], 0, 0, 0, 0x7f7f7f7f, 0, 0x7f7f7f7f);
    }
    __syncthreads();
  }

  float lp[4];
  #pragma unroll
  for (int n = 0; n < 4; ++n)
    lp[n] = lowpass[n0 + wcol * 64 + n * 16 + l15];

  #pragma unroll
  for (int m = 0; m < 2; ++m) {
    #pragma unroll
    for (int r = 0; r < 4; ++r) {
      int rg = row0 + wrow * 32 + m * 16 + l4 * 4 + r;
      float psum = 0.f;
      #pragma unroll
      for (int n = 0; n < 4; ++n) {
        float v = fabsf(acc[m][n][r]);
        psum += v * lp[n];
        int colg = n0 + wcol * 64 + n * 16 + l15;
        size_t si = ((size_t)((rg >> 4) * 8 + j) * 16 + (rg & 15)) * ND + colg;
        int pk = __builtin_amdgcn_cvt_pk_fp8_f32(v, v, 0, false);
        Sout[si] = (unsigned char)(pk & 0xff);
      }
      psum += __shfl_xor(psum, 1);
      psum += __shfl_xor(psum, 2);
      psum += __shfl_xor(psum, 4);
      psum += __shfl_xor(psum, 8);
      if (l15 == 0) {
        int pidx = rg * 73 + 1 + j;
        atomicAdd(&phi[pidx], psum);
      }
    }
  }
}

// ==== layer-2: MX-fp8, 256x256 tile, 8 waves (128x64), LDS dbuf, 2-barrier ====
// 256 blocks = exactly 1/CU (all resident, j-pure). Confirmed optimum.

__device__ __forceinline__ void stage256(const unsigned char* __restrict__ A, int row0,
                                         const unsigned char* __restrict__ Bj, int n0,
                                         int k0, unsigned char* As, unsigned char* Bs,
                                         int tid) {
  #pragma unroll
  for (int p = 0; p < 4; ++p) {
    int c = p * 512 + tid;
    int r = c >> 3;
    int s = (c & 7) ^ (r & 7);
    gload_lds16(A + (size_t)(row0 + r) * ND + k0 + (s << 4), As + c * 16);
  }
  #pragma unroll
  for (int p = 0; p < 4; ++p) {
    int c = p * 512 + tid;
    int r = c >> 3;
    int s = (c & 7) ^ (r & 7);
    gload_lds16(Bj + (size_t)(n0 + r) * ND + k0 + (s << 4), Bs + c * 16);
  }
}

__device__ __forceinline__ void compute256(const unsigned char* As, const unsigned char* Bs,
                                           f32x4 (&acc)[8][4],
                                           int wrow, int wcol, int l15, int l4) {
  i32x8 b[4];
  #pragma unroll
  for (int n = 0; n < 4; ++n)
    b[n] = dsr_frag8(Bs, wcol * 64 + n * 16 + l15, l4);
  #pragma unroll
  for (int m = 0; m < 8; ++m) {
    i32x8 a = dsr_frag8(As, wrow * 128 + m * 16 + l15, l4);
    #pragma unroll
    for (int n = 0; n < 4; ++n)
      acc[m][n] = __builtin_amdgcn_mfma_scale_f32_16x16x128_f8f6f4(
          a, b[n], acc[m][n], 0, 0, 0, 0x7f7f7f7f, 0, 0x7f7f7f7f);
  }
}

__global__ __launch_bounds__(512, 1)
void gemm8_l2(const unsigned char* __restrict__ A,
              const unsigned char* __restrict__ BT,
              const float* __restrict__ lowpass,
              float* __restrict__ phi) {
  __shared__ __align__(16) unsigned char As0[256 * 128];
  __shared__ __align__(16) unsigned char As1[256 * 128];
  __shared__ __align__(16) unsigned char Bs0[256 * 128];
  __shared__ __align__(16) unsigned char Bs1[256 * 128];

  const int tid  = threadIdx.x;
  const int lane = tid & 63;
  const int w    = tid >> 6;          // 8 waves: 2M x 4N
  const int wrow = w >> 2, wcol = w & 3;
  const int l15  = lane & 15, l4 = lane >> 4;

  const int wg = blockIdx.x;
  const int j  = wg & 7;              // XCD-pure (256 blocks, 1/CU)
  const int t  = wg >> 3;             // 0..31
  const int mtile = t & 7, ntile = t >> 3;
  const int row0 = mtile * 256, n0 = ntile * 256;
  const unsigned char* Bj = BT + (size_t)j * NNE;

  f32x4 acc[8][4] = {};

  stage256(A, row0, Bj, n0, 0, As0, Bs0, tid);
  __syncthreads();

  #pragma unroll 1
  for (int k0 = 0; k0 < ND; k0 += 128) {
    const int cur = (k0 >> 7) & 1;
    const unsigned char* Ac = cur ? As1 : As0;
    const unsigned char* Bc = cur ? Bs1 : Bs0;
    if (k0 + 128 < ND)
      stage256(A, row0, Bj, n0, k0 + 128, cur ? As0 : As1, cur ? Bs0 : Bs1, tid);
    compute256(Ac, Bc, acc, wrow, wcol, l15, l4);
    __syncthreads();
  }

  float lp[4];
  #pragma unroll
  for (int n = 0; n < 4; ++n)
    lp[n] = lowpass[n0 + wcol * 64 + n * 16 + l15];

  #pragma unroll
  for (int m = 0; m < 8; ++m) {
    #pragma unroll
    for (int r = 0; r < 4; ++r) {
      int rg = row0 + wrow * 128 + m * 16 + l4 * 4 + r;
      float psum = 0.f;
      #pragma unroll
      for (int n = 0; n < 4; ++n)
        psum += fabsf(acc[m][n][r]) * lp[n];
      psum += __shfl_xor(psum, 1);
      psum += __shfl_xor(psum, 2);
      psum += __shfl_xor(psum, 4);
      psum += __shfl_xor(psum, 8);
      if (l15 == 0) {
        int pidx = ((rg >> 7) * 16 + (rg & 15)) * 73 + 9 + ((rg >> 4) & 7) * 8 + j;
        atomicAdd(&phi[pidx], psum);
      }
    }
  }
}

extern "C" void kernel_launch(void* const* d_in, const int* in_sizes, int n_in,
                              void* d_out, int out_size, void* d_ws, size_t ws_size,
                              hipStream_t stream) {
  (void)in_sizes; (void)n_in; (void)ws_size; (void)out_size;
  const float* x       = (const float*)d_in[0];
  const float* psi     = (const float*)d_in[1];
  const float* lowpass = (const float*)d_in[2];
  float* phi = (float*)d_out;

  unsigned char* x8    = (unsigned char*)d_ws;                        // 256 KB (fp8 x)
  unsigned char* psiT8 = (unsigned char*)((char*)d_ws + (1u << 20));  // 8 MB  (fp8 psi^T)
  unsigned char* S1f8  = (unsigned char*)((char*)d_ws + (10u << 20)); // 2 MB  (fp8 S1)

  prep_kernel<<<768, 256, 0, stream>>>(psi, psiT8, x, lowpass, x8, phi);

  // layer 1: M=256, 64x128 tiles -> 256 blocks (full GPU, 1/CU, j-pure)
  gemm8_l1<<<256, 256, 0, stream>>>(x8, psiT8, lowpass, S1f8, phi);

  // layer 2: 256x256 tiles, 256 blocks (1/CU, all resident), 8 waves, dbuf LDS
  gemm8_l2<<<256, 512, 0, stream>>>(S1f8, psiT8, lowpass, phi);
}

// Round 27
// 57.081 us; speedup vs baseline: 1.0022x; 1.0022x over previous
//
#include <hip/hip_runtime.h>

#define ND 1024
#define NNE (ND*ND)

typedef float f32x4 __attribute__((ext_vector_type(4)));
typedef int i32x4 __attribute__((ext_vector_type(4)));
typedef int i32x8 __attribute__((ext_vector_type(8)));

__device__ __forceinline__ void gload_lds16(const void* g, void* l) {
  __builtin_amdgcn_global_load_lds(
      (const __attribute__((address_space(1))) void*)g,
      (__attribute__((address_space(3))) void*)l, 16, 0, 0);
}

// ==== fused prep: 512 transpose blocks + 256 convert/phi0 blocks ====
// transpose grid: j = blk&7 -> psi^T[j] written from XCD j (round-robin
// dispatch), so each 1 MB psi^T[j] stays in XCD j's local L2 for the
// j-pure GEMM readers.
__global__ __launch_bounds__(256)
void prep_kernel(const float* __restrict__ psi, unsigned char* __restrict__ out8,
                 const float* __restrict__ x, const float* __restrict__ lp,
                 unsigned char* __restrict__ x8, float* __restrict__ phi) {
  __shared__ __align__(16) unsigned char T[128 * 144];
  __shared__ float ws[4];
  const int blk = blockIdx.x;
  const int tid = threadIdx.x;

  if (blk >= 512) {
    int row = blk - 512;
    if (tid >= 1 && tid < 73) phi[row * 73 + tid] = 0.f;
    float4 v = reinterpret_cast<const float4*>(x + (size_t)row * ND)[tid];
    float4 l = reinterpret_cast<const float4*>(lp)[tid];
    int pk = __builtin_amdgcn_cvt_pk_fp8_f32(v.x, v.y, 0, false);
    pk = __builtin_amdgcn_cvt_pk_fp8_f32(v.z, v.w, pk, true);
    reinterpret_cast<unsigned int*>(x8 + (size_t)row * ND)[tid] = (unsigned int)pk;
    float s = v.x * l.x + v.y * l.y + v.z * l.z + v.w * l.w;
    #pragma unroll
    for (int off = 32; off; off >>= 1) s += __shfl_xor(s, off);
    if ((tid & 63) == 0) ws[tid >> 6] = s;
    __syncthreads();
    if (tid == 0) phi[row * 73] = ws[0] + ws[1] + ws[2] + ws[3];
    return;
  }

  const int j  = blk & 7;              // XCD-pure writer for psi^T[j]
  const int t6 = blk >> 3;             // 0..63
  const int tn = t6 >> 3, tm = t6 & 7;
  const int n0 = tn * 128, m0 = tm * 128;
  const float* src = psi + ((size_t)j << 20) + (size_t)n0 * ND + m0;

  const int rgrp = tid >> 5;
  const int c4   = (tid & 31) << 2;
  #pragma unroll
  for (int it = 0; it < 16; ++it) {
    int nl = it * 8 + rgrp;
    float4 v = *reinterpret_cast<const float4*>(src + (size_t)nl * ND + c4);
    int p01 = __builtin_amdgcn_cvt_pk_fp8_f32(v.x, v.y, 0, false);
    int p23 = __builtin_amdgcn_cvt_pk_fp8_f32(v.z, v.w, 0, false);
    T[(c4 + 0) * 144 + nl] = (unsigned char)(p01 & 0xff);
    T[(c4 + 1) * 144 + nl] = (unsigned char)((p01 >> 8) & 0xff);
    T[(c4 + 2) * 144 + nl] = (unsigned char)(p23 & 0xff);
    T[(c4 + 3) * 144 + nl] = (unsigned char)((p23 >> 8) & 0xff);
  }
  __syncthreads();

  unsigned char* dst = out8 + ((size_t)j << 20) + (size_t)m0 * ND + n0;
  const int mrow = tid >> 3;
  const int ch   = (tid & 7) << 4;
  #pragma unroll
  for (int it = 0; it < 4; ++it) {
    int ml = it * 32 + mrow;
    uint4 v = *reinterpret_cast<const uint4*>(&T[ml * 144 + ch]);
    *reinterpret_cast<uint4*>(dst + (size_t)ml * ND + ch) = v;
  }
}

// one 32B fp8 fragment from swizzled LDS (two ds_read_b128, k-order preserved)
__device__ __forceinline__ i32x8 dsr_frag8(const unsigned char* base, int r, int l4) {
  int s0 = l4 * 2;
  i32x4 lo = *reinterpret_cast<const i32x4*>(base + r * 128 + ((s0 ^ (r & 7)) << 4));
  i32x4 hi = *reinterpret_cast<const i32x4*>(base + r * 128 + (((s0 + 1) ^ (r & 7)) << 4));
  return __builtin_shufflevector(lo, hi, 0, 1, 2, 3, 4, 5, 6, 7);
}

// ==== layer-1: MX-fp8, 64x128 tile, 256 blocks (full GPU), LDS dbuf ====
__device__ __forceinline__ void stage_l1(const unsigned char* __restrict__ A, int row0,
                                         const unsigned char* __restrict__ Bj, int n0,
                                         int k0, unsigned char* As, unsigned char* Bs,
                                         int tid) {
  #pragma unroll
  for (int p = 0; p < 2; ++p) {
    int c = p * 256 + tid;
    int r = c >> 3;
    int s = (c & 7) ^ (r & 7);
    gload_lds16(A + (size_t)(row0 + r) * ND + k0 + (s << 4), As + c * 16);
  }
  #pragma unroll
  for (int p = 0; p < 4; ++p) {
    int c = p * 256 + tid;
    int r = c >> 3;
    int s = (c & 7) ^ (r & 7);
    gload_lds16(Bj + (size_t)(n0 + r) * ND + k0 + (s << 4), Bs + c * 16);
  }
}

__global__ __launch_bounds__(256, 2)
void gemm8_l1(const unsigned char* __restrict__ A,
              const unsigned char* __restrict__ BT,
              const float* __restrict__ lowpass,
              unsigned char* __restrict__ Sout,
              float* __restrict__ phi) {
  __shared__ __align__(16) unsigned char As0[64 * 128];
  __shared__ __align__(16) unsigned char As1[64 * 128];
  __shared__ __align__(16) unsigned char Bs0[128 * 128];
  __shared__ __align__(16) unsigned char Bs1[128 * 128];

  const int tid  = threadIdx.x;
  const int lane = tid & 63;
  const int w    = tid >> 6;
  const int wrow = w >> 1, wcol = w & 1;
  const int l15  = lane & 15, l4 = lane >> 4;

  const int wg = blockIdx.x;
  const int j  = wg & 7;
  const int t  = wg >> 3;
  const int mtile = t & 3, ntile = t >> 2;
  const int row0 = mtile * 64, n0 = ntile * 128;
  const unsigned char* Bj = BT + (size_t)j * NNE;

  f32x4 acc[2][4] = {};

  stage_l1(A, row0, Bj, n0, 0, As0, Bs0, tid);
  __syncthreads();

  #pragma unroll 1
  for (int k0 = 0; k0 < ND; k0 += 128) {
    const int cur = (k0 >> 7) & 1;
    const unsigned char* Ac = cur ? As1 : As0;
    const unsigned char* Bc = cur ? Bs1 : Bs0;
    if (k0 + 128 < ND)
      stage_l1(A, row0, Bj, n0, k0 + 128, cur ? As0 : As1, cur ? Bs0 : Bs1, tid);
    i32x8 b[4];
    #pragma unroll
    for (int n = 0; n < 4; ++n)
      b[n] = dsr_frag8(Bc, wcol * 64 + n * 16 + l15, l4);
    #pragma unroll
    for (int m = 0; m < 2; ++m) {
      i32x8 a = dsr_frag8(Ac, wrow * 32 + m * 16 + l15, l4);
      #pragma unroll
      for (int n = 0; n < 4; ++n)
        acc[m][n] = __builtin_amdgcn_mfma_scale_f32_16x16x128_f8f6f4(
            a, b[n], acc[m][n], 0, 0, 0, 0x7f7f7f7f, 0, 0x7f7f7f7f);
    }
    __syncthreads();
  }

  float lp[4];
  #pragma unroll
  for (int n = 0; n < 4; ++n)
    lp[n] = lowpass[n0 + wcol * 64 + n * 16 + l15];

  #pragma unroll
  for (int m = 0; m < 2; ++m) {
    #pragma unroll
    for (int r = 0; r < 4; ++r) {
      int rg = row0 + wrow * 32 + m * 16 + l4 * 4 + r;
      float psum = 0.f;
      #pragma unroll
      for (int n = 0; n < 4; ++n) {
        float v = fabsf(acc[m][n][r]);
        psum += v * lp[n];
        int colg = n0 + wcol * 64 + n * 16 + l15;
        size_t si = ((size_t)((rg >> 4) * 8 + j) * 16 + (rg & 15)) * ND + colg;
        int pk = __builtin_amdgcn_cvt_pk_fp8_f32(v, v, 0, false);
        Sout[si] = (unsigned char)(pk & 0xff);
      }
      psum += __shfl_xor(psum, 1);
      psum += __shfl_xor(psum, 2);
      psum += __shfl_xor(psum, 4);
      psum += __shfl_xor(psum, 8);
      if (l15 == 0) {
        int pidx = rg * 73 + 1 + j;
        atomicAdd(&phi[pidx], psum);
      }
    }
  }
}

// ==== layer-2: MX-fp8, 256x256 tile, 8 waves (128x64), LDS dbuf, 2-barrier ====
// 256 blocks = exactly 1/CU (all resident, j-pure). Confirmed optimum.

__device__ __forceinline__ void stage256(const unsigned char* __restrict__ A, int row0,
                                         const unsigned char* __restrict__ Bj, int n0,
                                         int k0, unsigned char* As, unsigned char* Bs,
                                         int tid) {
  #pragma unroll
  for (int p = 0; p < 4; ++p) {
    int c = p * 512 + tid;
    int r = c >> 3;
    int s = (c & 7) ^ (r & 7);
    gload_lds16(A + (size_t)(row0 + r) * ND + k0 + (s << 4), As + c * 16);
  }
  #pragma unroll
  for (int p = 0; p < 4; ++p) {
    int c = p * 512 + tid;
    int r = c >> 3;
    int s = (c & 7) ^ (r & 7);
    gload_lds16(Bj + (size_t)(n0 + r) * ND + k0 + (s << 4), Bs + c * 16);
  }
}

__device__ __forceinline__ void compute256(const unsigned char* As, const unsigned char* Bs,
                                           f32x4 (&acc)[8][4],
                                           int wrow, int wcol, int l15, int l4) {
  i32x8 b[4];
  #pragma unroll
  for (int n = 0; n < 4; ++n)
    b[n] = dsr_frag8(Bs, wcol * 64 + n * 16 + l15, l4);
  #pragma unroll
  for (int m = 0; m < 8; ++m) {
    i32x8 a = dsr_frag8(As, wrow * 128 + m * 16 + l15, l4);
    #pragma unroll
    for (int n = 0; n < 4; ++n)
      acc[m][n] = __builtin_amdgcn_mfma_scale_f32_16x16x128_f8f6f4(
          a, b[n], acc[m][n], 0, 0, 0, 0x7f7f7f7f, 0, 0x7f7f7f7f);
  }
}

__global__ __launch_bounds__(512, 1)
void gemm8_l2(const unsigned char* __restrict__ A,
              const unsigned char* __restrict__ BT,
              const float* __restrict__ lowpass,
              float* __restrict__ phi) {
  __shared__ __align__(16) unsigned char As0[256 * 128];
  __shared__ __align__(16) unsigned char As1[256 * 128];
  __shared__ __align__(16) unsigned char Bs0[256 * 128];
  __shared__ __align__(16) unsigned char Bs1[256 * 128];

  const int tid  = threadIdx.x;
  const int lane = tid & 63;
  const int w    = tid >> 6;          // 8 waves: 2M x 4N
  const int wrow = w >> 2, wcol = w & 3;
  const int l15  = lane & 15, l4 = lane >> 4;

  const int wg = blockIdx.x;
  const int j  = wg & 7;              // XCD-pure (256 blocks, 1/CU)
  const int t  = wg >> 3;             // 0..31
  const int mtile = t & 7, ntile = t >> 3;
  const int row0 = mtile * 256, n0 = ntile * 256;
  const unsigned char* Bj = BT + (size_t)j * NNE;

  f32x4 acc[8][4] = {};

  stage256(A, row0, Bj, n0, 0, As0, Bs0, tid);
  __syncthreads();

  #pragma unroll 1
  for (int k0 = 0; k0 < ND; k0 += 128) {
    const int cur = (k0 >> 7) & 1;
    const unsigned char* Ac = cur ? As1 : As0;
    const unsigned char* Bc = cur ? Bs1 : Bs0;
    if (k0 + 128 < ND)
      stage256(A, row0, Bj, n0, k0 + 128, cur ? As0 : As1, cur ? Bs0 : Bs1, tid);
    compute256(Ac, Bc, acc, wrow, wcol, l15, l4);
    __syncthreads();
  }

  float lp[4];
  #pragma unroll
  for (int n = 0; n < 4; ++n)
    lp[n] = lowpass[n0 + wcol * 64 + n * 16 + l15];

  #pragma unroll
  for (int m = 0; m < 8; ++m) {
    #pragma unroll
    for (int r = 0; r < 4; ++r) {
      int rg = row0 + wrow * 128 + m * 16 + l4 * 4 + r;
      float psum = 0.f;
      #pragma unroll
      for (int n = 0; n < 4; ++n)
        psum += fabsf(acc[m][n][r]) * lp[n];
      psum += __shfl_xor(psum, 1);
      psum += __shfl_xor(psum, 2);
      psum += __shfl_xor(psum, 4);
      psum += __shfl_xor(psum, 8);
      if (l15 == 0) {
        int pidx = ((rg >> 7) * 16 + (rg & 15)) * 73 + 9 + ((rg >> 4) & 7) * 8 + j;
        atomicAdd(&phi[pidx], psum);
      }
    }
  }
}

extern "C" void kernel_launch(void* const* d_in, const int* in_sizes, int n_in,
                              void* d_out, int out_size, void* d_ws, size_t ws_size,
                              hipStream_t stream) {
  (void)in_sizes; (void)n_in; (void)ws_size; (void)out_size;
  const float* x       = (const float*)d_in[0];
  const float* psi     = (const float*)d_in[1];
  const float* lowpass = (const float*)d_in[2];
  float* phi = (float*)d_out;

  unsigned char* x8    = (unsigned char*)d_ws;                        // 256 KB (fp8 x)
  unsigned char* psiT8 = (unsigned char*)((char*)d_ws + (1u << 20));  // 8 MB  (fp8 psi^T)
  unsigned char* S1f8  = (unsigned char*)((char*)d_ws + (10u << 20)); // 2 MB  (fp8 S1)

  prep_kernel<<<768, 256, 0, stream>>>(psi, psiT8, x, lowpass, x8, phi);

  // layer 1: M=256, 64x128 tiles -> 256 blocks (full GPU, 1/CU, j-pure)
  gemm8_l1<<<256, 256, 0, stream>>>(x8, psiT8, lowpass, S1f8, phi);

  // layer 2: 256x256 tiles, 256 blocks (1/CU, all resident), 8 waves, dbuf LDS
  gemm8_l2<<<256, 512, 0, stream>>>(S1f8, psiT8, lowpass, phi);
}

// Round 28
// 56.969 us; speedup vs baseline: 1.0042x; 1.0020x over previous
//
#include <hip/hip_runtime.h>

#define ND 1024
#define NNE (ND*ND)

typedef float f32x4 __attribute__((ext_vector_type(4)));
typedef int i32x4 __attribute__((ext_vector_type(4)));
typedef int i32x8 __attribute__((ext_vector_type(8)));

__device__ __forceinline__ void gload_lds16(const void* g, void* l) {
  __builtin_amdgcn_global_load_lds(
      (const __attribute__((address_space(1))) void*)g,
      (__attribute__((address_space(3))) void*)l, 16, 0, 0);
}

// ==== fused prep: 512 transpose blocks + 256 convert/phi0 blocks ====
// transpose grid: j = blk&7 -> psi^T[j] written from XCD j (round-robin
// dispatch), so each 1 MB psi^T[j] stays in XCD j's local L2 for the
// j-pure GEMM readers.
__global__ __launch_bounds__(256)
void prep_kernel(const float* __restrict__ psi, unsigned char* __restrict__ out8,
                 const float* __restrict__ x, const float* __restrict__ lp,
                 unsigned char* __restrict__ x8, float* __restrict__ phi) {
  __shared__ __align__(16) unsigned char T[128 * 144];
  __shared__ float ws[4];
  const int blk = blockIdx.x;
  const int tid = threadIdx.x;

  if (blk >= 512) {
    int row = blk - 512;
    if (tid >= 1 && tid < 73) phi[row * 73 + tid] = 0.f;
    float4 v = reinterpret_cast<const float4*>(x + (size_t)row * ND)[tid];
    float4 l = reinterpret_cast<const float4*>(lp)[tid];
    int pk = __builtin_amdgcn_cvt_pk_fp8_f32(v.x, v.y, 0, false);
    pk = __builtin_amdgcn_cvt_pk_fp8_f32(v.z, v.w, pk, true);
    reinterpret_cast<unsigned int*>(x8 + (size_t)row * ND)[tid] = (unsigned int)pk;
    float s = v.x * l.x + v.y * l.y + v.z * l.z + v.w * l.w;
    #pragma unroll
    for (int off = 32; off; off >>= 1) s += __shfl_xor(s, off);
    if ((tid & 63) == 0) ws[tid >> 6] = s;
    __syncthreads();
    if (tid == 0) phi[row * 73] = ws[0] + ws[1] + ws[2] + ws[3];
    return;
  }

  const int j  = blk & 7;              // XCD-pure writer for psi^T[j]
  const int t6 = blk >> 3;             // 0..63
  const int tn = t6 >> 3, tm = t6 & 7;
  const int n0 = tn * 128, m0 = tm * 128;
  const float* src = psi + ((size_t)j << 20) + (size_t)n0 * ND + m0;

  const int rgrp = tid >> 5;
  const int c4   = (tid & 31) << 2;
  #pragma unroll
  for (int it = 0; it < 16; ++it) {
    int nl = it * 8 + rgrp;
    float4 v = *reinterpret_cast<const float4*>(src + (size_t)nl * ND + c4);
    int p01 = __builtin_amdgcn_cvt_pk_fp8_f32(v.x, v.y, 0, false);
    int p23 = __builtin_amdgcn_cvt_pk_fp8_f32(v.z, v.w, 0, false);
    T[(c4 + 0) * 144 + nl] = (unsigned char)(p01 & 0xff);
    T[(c4 + 1) * 144 + nl] = (unsigned char)((p01 >> 8) & 0xff);
    T[(c4 + 2) * 144 + nl] = (unsigned char)(p23 & 0xff);
    T[(c4 + 3) * 144 + nl] = (unsigned char)((p23 >> 8) & 0xff);
  }
  __syncthreads();

  unsigned char* dst = out8 + ((size_t)j << 20) + (size_t)m0 * ND + n0;
  const int mrow = tid >> 3;
  const int ch   = (tid & 7) << 4;
  #pragma unroll
  for (int it = 0; it < 4; ++it) {
    int ml = it * 32 + mrow;
    uint4 v = *reinterpret_cast<const uint4*>(&T[ml * 144 + ch]);
    *reinterpret_cast<uint4*>(dst + (size_t)ml * ND + ch) = v;
  }
}

// one 32B fp8 fragment from swizzled LDS (two ds_read_b128, k-order preserved)
__device__ __forceinline__ i32x8 dsr_frag8(const unsigned char* base, int r, int l4) {
  int s0 = l4 * 2;
  i32x4 lo = *reinterpret_cast<const i32x4*>(base + r * 128 + ((s0 ^ (r & 7)) << 4));
  i32x4 hi = *reinterpret_cast<const i32x4*>(base + r * 128 + (((s0 + 1) ^ (r & 7)) << 4));
  return __builtin_shufflevector(lo, hi, 0, 1, 2, 3, 4, 5, 6, 7);
}

// ==== layer-1: MX-fp8, 64x128 tile, 256 blocks (full GPU), LDS dbuf ====
__device__ __forceinline__ void stage_l1(const unsigned char* __restrict__ A, int row0,
                                         const unsigned char* __restrict__ Bj, int n0,
                                         int k0, unsigned char* As, unsigned char* Bs,
                                         int tid) {
  #pragma unroll
  for (int p = 0; p < 2; ++p) {
    int c = p * 256 + tid;
    int r = c >> 3;
    int s = (c & 7) ^ (r & 7);
    gload_lds16(A + (size_t)(row0 + r) * ND + k0 + (s << 4), As + c * 16);
  }
  #pragma unroll
  for (int p = 0; p < 4; ++p) {
    int c = p * 256 + tid;
    int r = c >> 3;
    int s = (c & 7) ^ (r & 7);
    gload_lds16(Bj + (size_t)(n0 + r) * ND + k0 + (s << 4), Bs + c * 16);
  }
}

__global__ __launch_bounds__(256, 2)
void gemm8_l1(const unsigned char* __restrict__ A,
              const unsigned char* __restrict__ BT,
              const float* __restrict__ lowpass,
              unsigned char* __restrict__ Sout,
              float* __restrict__ phi) {
  __shared__ __align__(16) unsigned char As0[64 * 128];
  __shared__ __align__(16) unsigned char As1[64 * 128];
  __shared__ __align__(16) unsigned char Bs0[128 * 128];
  __shared__ __align__(16) unsigned char Bs1[128 * 128];

  const int tid  = threadIdx.x;
  const int lane = tid & 63;
  const int w    = tid >> 6;
  const int wrow = w >> 1, wcol = w & 1;
  const int l15  = lane & 15, l4 = lane >> 4;

  const int wg = blockIdx.x;
  const int j  = wg & 7;
  const int t  = wg >> 3;
  const int mtile = t & 3, ntile = t >> 2;
  const int row0 = mtile * 64, n0 = ntile * 128;
  const unsigned char* Bj = BT + (size_t)j * NNE;

  f32x4 acc[2][4] = {};

  stage_l1(A, row0, Bj, n0, 0, As0, Bs0, tid);
  __syncthreads();

  #pragma unroll 1
  for (int k0 = 0; k0 < ND; k0 += 128) {
    const int cur = (k0 >> 7) & 1;
    const unsigned char* Ac = cur ? As1 : As0;
    const unsigned char* Bc = cur ? Bs1 : Bs0;
    if (k0 + 128 < ND)
      stage_l1(A, row0, Bj, n0, k0 + 128, cur ? As0 : As1, cur ? Bs0 : Bs1, tid);
    i32x8 b[4];
    #pragma unroll
    for (int n = 0; n < 4; ++n)
      b[n] = dsr_frag8(Bc, wcol * 64 + n * 16 + l15, l4);
    #pragma unroll
    for (int m = 0; m < 2; ++m) {
      i32x8 a = dsr_frag8(Ac, wrow * 32 + m * 16 + l15, l4);
      #pragma unroll
      for (int n = 0; n < 4; ++n)
        acc[m][n] = __builtin_amdgcn_mfma_scale_f32_16x16x128_f8f6f4(
            a, b[n], acc[m][n], 0, 0, 0, 0x7f7f7f7f, 0, 0x7f7f7f7f);
    }
    __syncthreads();
  }

  float lp[4];
  #pragma unroll
  for (int n = 0; n < 4; ++n)
    lp[n] = lowpass[n0 + wcol * 64 + n * 16 + l15];

  #pragma unroll
  for (int m = 0; m < 2; ++m) {
    #pragma unroll
    for (int r = 0; r < 4; ++r) {
      int rg = row0 + wrow * 32 + m * 16 + l4 * 4 + r;
      float psum = 0.f;
      #pragma unroll
      for (int n = 0; n < 4; ++n) {
        float v = fabsf(acc[m][n][r]);
        psum += v * lp[n];
        int colg = n0 + wcol * 64 + n * 16 + l15;
        size_t si = ((size_t)((rg >> 4) * 8 + j) * 16 + (rg & 15)) * ND + colg;
        int pk = __builtin_amdgcn_cvt_pk_fp8_f32(v, v, 0, false);
        Sout[si] = (unsigned char)(pk & 0xff);
      }
      psum += __shfl_xor(psum, 1);
      psum += __shfl_xor(psum, 2);
      psum += __shfl_xor(psum, 4);
      psum += __shfl_xor(psum, 8);
      if (l15 == 0) {
        int pidx = rg * 73 + 1 + j;
        atomicAdd(&phi[pidx], psum);
      }
    }
  }
}

// ==== layer-2: MX-fp8, 256x256 tile, 8 waves (128x64), LDS dbuf, 2-barrier ====
// 256 blocks = exactly 1/CU (all resident, j-pure). Confirmed optimum.

__device__ __forceinline__ void stage256(const unsigned char* __restrict__ A, int row0,
                                         const unsigned char* __restrict__ Bj, int n0,
                                         int k0, unsigned char* As, unsigned char* Bs,
                                         int tid) {
  #pragma unroll
  for (int p = 0; p < 4; ++p) {
    int c = p * 512 + tid;
    int r = c >> 3;
    int s = (c & 7) ^ (r & 7);
    gload_lds16(A + (size_t)(row0 + r) * ND + k0 + (s << 4), As + c * 16);
  }
  #pragma unroll
  for (int p = 0; p < 4; ++p) {
    int c = p * 512 + tid;
    int r = c >> 3;
    int s = (c & 7) ^ (r & 7);
    gload_lds16(Bj + (size_t)(n0 + r) * ND + k0 + (s << 4), Bs + c * 16);
  }
}

__device__ __forceinline__ void compute256(const unsigned char* As, const unsigned char* Bs,
                                           f32x4 (&acc)[8][4],
                                           int wrow, int wcol, int l15, int l4) {
  i32x8 b[4];
  #pragma unroll
  for (int n = 0; n < 4; ++n)
    b[n] = dsr_frag8(Bs, wcol * 64 + n * 16 + l15, l4);
  #pragma unroll
  for (int m = 0; m < 8; ++m) {
    i32x8 a = dsr_frag8(As, wrow * 128 + m * 16 + l15, l4);
    #pragma unroll
    for (int n = 0; n < 4; ++n)
      acc[m][n] = __builtin_amdgcn_mfma_scale_f32_16x16x128_f8f6f4(
          a, b[n], acc[m][n], 0, 0, 0, 0x7f7f7f7f, 0, 0x7f7f7f7f);
  }
}

__global__ __launch_bounds__(512, 1)
void gemm8_l2(const unsigned char* __restrict__ A,
              const unsigned char* __restrict__ BT,
              const float* __restrict__ lowpass,
              float* __restrict__ phi) {
  __shared__ __align__(16) unsigned char As0[256 * 128];
  __shared__ __align__(16) unsigned char As1[256 * 128];
  __shared__ __align__(16) unsigned char Bs0[256 * 128];
  __shared__ __align__(16) unsigned char Bs1[256 * 128];

  const int tid  = threadIdx.x;
  const int lane = tid & 63;
  const int w    = tid >> 6;          // 8 waves: 2M x 4N
  const int wrow = w >> 2, wcol = w & 3;
  const int l15  = lane & 15, l4 = lane >> 4;

  const int wg = blockIdx.x;
  const int j  = wg & 7;              // XCD-pure (256 blocks, 1/CU)
  const int t  = wg >> 3;             // 0..31
  const int mtile = t & 7, ntile = t >> 3;
  const int row0 = mtile * 256, n0 = ntile * 256;
  const unsigned char* Bj = BT + (size_t)j * NNE;

  f32x4 acc[8][4] = {};

  stage256(A, row0, Bj, n0, 0, As0, Bs0, tid);
  __syncthreads();

  #pragma unroll 1
  for (int k0 = 0; k0 < ND; k0 += 128) {
    const int cur = (k0 >> 7) & 1;
    const unsigned char* Ac = cur ? As1 : As0;
    const unsigned char* Bc = cur ? Bs1 : Bs0;
    if (k0 + 128 < ND)
      stage256(A, row0, Bj, n0, k0 + 128, cur ? As0 : As1, cur ? Bs0 : Bs1, tid);
    compute256(Ac, Bc, acc, wrow, wcol, l15, l4);
    __syncthreads();
  }

  float lp[4];
  #pragma unroll
  for (int n = 0; n < 4; ++n)
    lp[n] = lowpass[n0 + wcol * 64 + n * 16 + l15];

  #pragma unroll
  for (int m = 0; m < 8; ++m) {
    #pragma unroll
    for (int r = 0; r < 4; ++r) {
      int rg = row0 + wrow * 128 + m * 16 + l4 * 4 + r;
      float psum = 0.f;
      #pragma unroll
      for (int n = 0; n < 4; ++n)
        psum += fabsf(acc[m][n][r]) * lp[n];
      psum += __shfl_xor(psum, 1);
      psum += __shfl_xor(psum, 2);
      psum += __shfl_xor(psum, 4);
      psum += __shfl_xor(psum, 8);
      if (l15 == 0) {
        int pidx = ((rg >> 7) * 16 + (rg & 15)) * 73 + 9 + ((rg >> 4) & 7) * 8 + j;
        atomicAdd(&phi[pidx], psum);
      }
    }
  }
}

extern "C" void kernel_launch(void* const* d_in, const int* in_sizes, int n_in,
                              void* d_out, int out_size, void* d_ws, size_t ws_size,
                              hipStream_t stream) {
  (void)in_sizes; (void)n_in; (void)ws_size; (void)out_size;
  const float* x       = (const float*)d_in[0];
  const float* psi     = (const float*)d_in[1];
  const float* lowpass = (const float*)d_in[2];
  float* phi = (float*)d_out;

  unsigned char* x8    = (unsigned char*)d_ws;                        // 256 KB (fp8 x)
  unsigned char* psiT8 = (unsigned char*)((char*)d_ws + (1u << 20));  // 8 MB  (fp8 psi^T)
  unsigned char* S1f8  = (unsigned char*)((char*)d_ws + (10u << 20)); // 2 MB  (fp8 S1)

  prep_kernel<<<768, 256, 0, stream>>>(psi, psiT8, x, lowpass, x8, phi);

  // layer 1: M=256, 64x128 tiles -> 256 blocks (full GPU, 1/CU, j-pure)
  gemm8_l1<<<256, 256, 0, stream>>>(x8, psiT8, lowpass, S1f8, phi);

  // layer 2: 256x256 tiles, 256 blocks (1/CU, all resident), 8 waves, dbuf LDS
  gemm8_l2<<<256, 512, 0, stream>>>(S1f8, psiT8, lowpass, phi);
}